// Round 6
// baseline (363.958 us; speedup 1.0000x reference)
//
#include <hip/hip_runtime.h>
#include <hip/hip_bf16.h>

#define LRELU_SLOPE 0.2f
#define CH2 6144          // edges per partition block (6 per thread, 1024 threads)
#define NBUK 256          // dst buckets (512 nodes each)
#define BCAP 9728         // per-bucket capacity (mean 8704, +11 sigma)

typedef unsigned int uint;
typedef unsigned short ushort;

__device__ __forceinline__ float lrelu(float a) {
    return a > 0.f ? a : LRELU_SLOPE * a;
}
__device__ __forceinline__ ushort f2bf(float f) {   // RNE
    uint u = __float_as_uint(f);
    return (ushort)((u + 0x7FFF + ((u >> 16) & 1)) >> 16);
}
__device__ __forceinline__ float bf2f(ushort h) {
    return __uint_as_float(((uint)h) << 16);
}

// ---------------- GEMM: X[nrows,K] @ W[K,64] -> OUT[nrows,64] in bf16 ----------------
template<int K>
__global__ __launch_bounds__(256) void gemm_bf16out(
    const float* __restrict__ X, const float* __restrict__ W,
    ushort* __restrict__ OUT, int nrows)
{
    __shared__ float xs[64][33];
    __shared__ float ws[32][64];
    const int tid = threadIdx.x;
    const int block_row = blockIdx.x * 64;
    const int tx = tid & 15, ty = tid >> 4;
    float acc[4][4] = {};

    for (int k0 = 0; k0 < K; k0 += 32) {
        #pragma unroll
        for (int half = 0; half < 2; ++half) {
            int r = (tid >> 3) + 32 * half;
            int kq = (tid & 7) * 4;
            int gr = block_row + r;
            float4 v = make_float4(0.f, 0.f, 0.f, 0.f);
            if (gr < nrows) v = *(const float4*)(X + (size_t)gr * K + k0 + kq);
            xs[r][kq + 0] = v.x; xs[r][kq + 1] = v.y;
            xs[r][kq + 2] = v.z; xs[r][kq + 3] = v.w;
        }
        #pragma unroll
        for (int half = 0; half < 2; ++half) {
            int i = tid + 256 * half;
            int r = i >> 4, cq = (i & 15) << 2;
            float4 w = *(const float4*)(W + (size_t)(k0 + r) * 64 + cq);
            *(float4*)&ws[r][cq] = w;
        }
        __syncthreads();
        #pragma unroll
        for (int kk = 0; kk < 32; ++kk) {
            float4 wv = *(const float4*)&ws[kk][tx << 2];
            float xr[4];
            #pragma unroll
            for (int i = 0; i < 4; ++i) xr[i] = xs[(ty << 2) + i][kk];
            #pragma unroll
            for (int i = 0; i < 4; ++i) {
                acc[i][0] += xr[i] * wv.x; acc[i][1] += xr[i] * wv.y;
                acc[i][2] += xr[i] * wv.z; acc[i][3] += xr[i] * wv.w;
            }
        }
        __syncthreads();
    }
    #pragma unroll
    for (int i = 0; i < 4; ++i) {
        int gr = block_row + (ty << 2) + i;
        if (gr < nrows) {
            uint2 o;
            o.x = (uint)f2bf(acc[i][0]) | ((uint)f2bf(acc[i][1]) << 16);
            o.y = (uint)f2bf(acc[i][2]) | ((uint)f2bf(acc[i][3]) << 16);
            *(uint2*)(OUT + (size_t)gr * 64 + (tx << 2)) = o;
        }
    }
}

// ---------------- per-node attention logits ----------------
__global__ __launch_bounds__(256) void node_att_h8(
    const ushort* __restrict__ H, const float* __restrict__ att_s,
    const float* __restrict__ att_d,
    float* __restrict__ a_src, float* __restrict__ a_dst, int n)
{
    int node = blockIdx.x * 4 + (threadIdx.x >> 6);
    if (node >= n) return;
    int lane = threadIdx.x & 63;
    float h = bf2f(H[(size_t)node * 64 + lane]);
    float ps = h * att_s[lane];
    float pd = h * att_d[lane];
    #pragma unroll
    for (int off = 1; off < 8; off <<= 1) {
        ps += __shfl_xor(ps, off, 64);
        pd += __shfl_xor(pd, off, 64);
    }
    if ((lane & 7) == 0) {
        a_src[(size_t)node * 8 + (lane >> 3)] = ps;
        a_dst[(size_t)node * 8 + (lane >> 3)] = pd;
    }
}

__global__ __launch_bounds__(256) void node_att_h1(
    const ushort* __restrict__ H, const float* __restrict__ att_s,
    const float* __restrict__ att_d,
    float* __restrict__ a_src, float* __restrict__ a_dst, int n)
{
    int node = blockIdx.x * 4 + (threadIdx.x >> 6);
    if (node >= n) return;
    int lane = threadIdx.x & 63;
    float h = bf2f(H[(size_t)node * 64 + lane]);
    float ps = h * att_s[lane];
    float pd = h * att_d[lane];
    #pragma unroll
    for (int off = 1; off < 64; off <<= 1) {
        ps += __shfl_xor(ps, off, 64);
        pd += __shfl_xor(pd, off, 64);
    }
    if (lane == 0) { a_src[node] = ps; a_dst[node] = pd; }
}

// ---------------- init per-bucket cursors ----------------
__global__ void init_pcur(int* __restrict__ pcur)
{
    int t = threadIdx.x;
    if (t < NBUK) pcur[t] = t * BCAP;
}

// ---- phase 1: register-held partition of edges into dst buckets ----
__global__ __launch_bounds__(1024) void partition_pairs(
    const int* __restrict__ ei, int E_, int ET,
    int* __restrict__ pcur, uint* __restrict__ pairs)
{
    __shared__ int lcnt[NBUK], lsc[NBUK], lplace[NBUK], gpos[NBUK];
    const int t = threadIdx.x;
    const int base = blockIdx.x * CH2;
    const int total = min(CH2, ET - base);
    if (total <= 0) return;

    if (t < NBUK) lcnt[t] = 0;
    __syncthreads();

    uint pp[6]; int pk[6];
    #pragma unroll
    for (int i = 0; i < 6; ++i) {
        int idx = t + i * 1024;
        pk[i] = -1;
        if (idx < total) {
            int e = base + idx;
            int s, d;
            if (e < E_) { s = ei[e]; d = ei[E_ + e]; } else { s = d = e - E_; }
            pk[i] = d >> 9;
            pp[i] = (uint)s | ((uint)(d & 511) << 17);
            atomicAdd(&lcnt[pk[i]], 1);
        }
    }
    __syncthreads();

    if (t < NBUK) lsc[t] = lcnt[t];
    __syncthreads();
    for (int off = 1; off < NBUK; off <<= 1) {
        int add = 0;
        if (t < NBUK && t >= off) add = lsc[t - off];
        __syncthreads();
        if (t < NBUK) lsc[t] += add;
        __syncthreads();
    }
    if (t < NBUK) {
        int excl = lsc[t] - lcnt[t];
        lplace[t] = excl;
        int c = lcnt[t];
        gpos[t] = c ? (atomicAdd(&pcur[t], c) - excl) : 0;
    }
    __syncthreads();

    #pragma unroll
    for (int i = 0; i < 6; ++i) {
        if (pk[i] >= 0) {
            int slot = atomicAdd(&lplace[pk[i]], 1);
            pairs[gpos[pk[i]] + slot] = pp[i];
        }
    }
}

// ---- exclusive scan of bucket totals -> boff (single block) ----
__global__ __launch_bounds__(256) void bucket_scan(
    const int* __restrict__ pcur, int* __restrict__ boff, int nbuk_used)
{
    __shared__ int sm[NBUK];
    int t = threadIdx.x;
    int v = (t < nbuk_used) ? (pcur[t] - t * BCAP) : 0;
    sm[t] = v; __syncthreads();
    for (int off = 1; off < NBUK; off <<= 1) {
        int add = (t >= off) ? sm[t - off] : 0;
        __syncthreads();
        sm[t] += add;
        __syncthreads();
    }
    boff[t] = sm[t] - v;   // exclusive
}

// ---- phase 2: per-bucket histogram + scan + scatter; writes rp AND ssrc ----
__global__ __launch_bounds__(1024) void phase2_build(
    const uint* __restrict__ pairs, const int* __restrict__ pcur,
    const int* __restrict__ boff,
    int* __restrict__ rp, int* __restrict__ ssrc, int n)
{
    __shared__ int hist[512], cur[512];
    const int k = blockIdx.x;
    const int t = threadIdx.x;
    const int beg = k * BCAP;
    const int cnt = pcur[k] - beg;
    const int bbase = boff[k];
    const int dbase = k << 9;

    if (t < 512) hist[t] = 0;
    __syncthreads();

    uint pp[10];
    int m = 0;
    for (int i = t; i < cnt; i += 1024) {
        uint p = pairs[beg + i];
        pp[m++] = p;
        atomicAdd(&hist[p >> 17], 1);
    }
    __syncthreads();

    int c0 = (t < 512) ? hist[t] : 0;
    for (int off = 1; off < 512; off <<= 1) {
        int add = 0;
        if (t < 512 && t >= off) add = hist[t - off];
        __syncthreads();
        if (t < 512) hist[t] += add;
        __syncthreads();
    }
    if (t < 512) {
        int node = dbase + t;
        if (node < n) rp[node] = bbase + hist[t];
        cur[t] = hist[t] - c0;
    }
    __syncthreads();

    m = 0;
    for (int i = t; i < cnt; i += 1024) {
        uint p = pp[m++];
        int j = p >> 17;
        int pos = bbase + atomicAdd(&cur[j], 1);
        ssrc[pos] = (int)(p & 0x1FFFF);
    }
}

// ---- pull-gather layer 1 (8 heads): lane-parallel score precompute ----
// Roles per lane: q = lane>>3, hh = lane&7.
//  score role: lane computes exp for edge (r*8+q) at head hh (8 rounds).
//  fma role:   lane owns channel `lane` (head q); pulls scores via bpermute.
__global__ __launch_bounds__(256) void gather_h8(
    const int* __restrict__ rp, const int* __restrict__ ssrc,
    const float* __restrict__ a_src, const float* __restrict__ a_dst,
    const ushort* __restrict__ HB, const float* __restrict__ bias,
    float* __restrict__ B, int n)
{
    int node = blockIdx.x * 4 + (threadIdx.x >> 6);
    if (node >= n) return;
    int lane = threadIdx.x & 63;
    int end = rp[node];
    int start = node ? rp[node - 1] : 0;
    int q  = lane >> 3;
    int hh = lane & 7;
    float adh = a_dst[(size_t)node * 8 + hh];
    float acc = 0.f, dpart = 0.f;

    for (int i0 = start; i0 < end; i0 += 64) {
        int cnt = min(64, end - i0);
        int sv = (i0 + lane < end) ? ssrc[i0 + lane] : 0;

        // 8 rounds: lane computes score for edge j=r*8+q at head hh
        float ex[8];
        #pragma unroll
        for (int r = 0; r < 8; ++r) {
            int j = r * 8 + q;
            int sj = __shfl(sv, j, 64);
            float a = a_src[(size_t)sj * 8 + hh] + adh;
            a = a > 0.f ? a : LRELU_SLOPE * a;
            float e = __expf(a);
            e = (j < cnt) ? e : 0.f;
            ex[r] = e;
            dpart += e;
        }
        // fma: edge j=g*8+k; score for (j, head q) lives in lane k*8+q, reg g
        #pragma unroll
        for (int g = 0; g < 8; ++g) {
            if (g * 8 < cnt) {
                #pragma unroll
                for (int k = 0; k < 8; ++k) {
                    int j = g * 8 + k;
                    float e = __shfl(ex[g], k * 8 + q, 64);
                    int sj = __shfl(sv, j, 64);
                    acc += e * bf2f(HB[(size_t)sj * 64 + lane]);
                }
            }
        }
    }
    // dpart = partial sum for head hh; reduce over lanes sharing hh (bits 3..5)
    dpart += __shfl_xor(dpart, 8, 64);
    dpart += __shfl_xor(dpart, 16, 64);
    dpart += __shfl_xor(dpart, 32, 64);
    float dsum = __shfl(dpart, q, 64);   // total for my head (lane q holds head q)
    float v = acc / (dsum + 1e-16f) + bias[lane];
    B[(size_t)node * 64 + lane] = v > 0.f ? v : expm1f(v);
}

// ---- pull-gather layer 2 (1 head): lane-parallel score precompute + lsm ----
__global__ __launch_bounds__(256) void gather_h1_lsm(
    const int* __restrict__ rp, const int* __restrict__ ssrc,
    const float* __restrict__ a_src, const float* __restrict__ a_dst,
    const ushort* __restrict__ HB, const float* __restrict__ bias,
    float* __restrict__ OUT, int n)
{
    int node = blockIdx.x * 4 + (threadIdx.x >> 6);
    if (node >= n) return;
    int lane = threadIdx.x & 63;
    int end = rp[node];
    int start = node ? rp[node - 1] : 0;
    float ad = a_dst[node];
    float acc = 0.f, dpart = 0.f;

    for (int i0 = start; i0 < end; i0 += 64) {
        int cnt = min(64, end - i0);
        int sv = (i0 + lane < end) ? ssrc[i0 + lane] : 0;
        // lane computes score for its own edge
        float a = a_src[sv] + ad;
        a = a > 0.f ? a : LRELU_SLOPE * a;
        float e = __expf(a);
        e = (lane < cnt) ? e : 0.f;
        dpart += e;

        for (int j0 = 0; j0 < cnt; j0 += 8) {
            #pragma unroll
            for (int k = 0; k < 8; ++k) {
                int j = j0 + k;
                float e2 = __shfl(e, j, 64);
                int sj = __shfl(sv, j, 64);
                acc += e2 * bf2f(HB[(size_t)sj * 64 + lane]);
            }
        }
    }
    #pragma unroll
    for (int off = 1; off < 64; off <<= 1) dpart += __shfl_xor(dpart, off, 64);

    float v = acc / (dpart + 1e-16f) + bias[lane];
    float m = v;
    #pragma unroll
    for (int off = 1; off < 64; off <<= 1) m = fmaxf(m, __shfl_xor(m, off));
    float exv = __expf(v - m);
    float sum = exv;
    #pragma unroll
    for (int off = 1; off < 64; off <<= 1) sum += __shfl_xor(sum, off);
    OUT[(size_t)node * 64 + lane] = v - m - __logf(sum);
}

extern "C" void kernel_launch(void* const* d_in, const int* in_sizes, int n_in,
                              void* d_out, int out_size, void* d_ws, size_t ws_size,
                              hipStream_t stream)
{
    const float* x    = (const float*)d_in[0];
    const int*   ei   = (const int*)d_in[1];
    const float* W1   = (const float*)d_in[2];
    const float* as1w = (const float*)d_in[3];
    const float* ad1w = (const float*)d_in[4];
    const float* b1   = (const float*)d_in[5];
    const float* W2   = (const float*)d_in[6];
    const float* as2w = (const float*)d_in[7];
    const float* ad2w = (const float*)d_in[8];
    const float* b2   = (const float*)d_in[9];
    float* out = (float*)d_out;

    const int n  = in_sizes[0] / 256;     // 100000
    const int E_ = in_sizes[1] / 2;       // 1600000
    const int ET = E_ + n;
    const int NBUKU = (n + 511) >> 9;     // 196 used buckets

    char* wsb = (char*)d_ws;
    float*  B    = (float*)wsb;                          // [n*64] f32 (aliases pairs)
    uint*   pairs= (uint*)wsb;                           // [NBUK*BCAP] (build-time only)
    ushort* HB   = (ushort*)(B + (size_t)n * 64);        // [n*64] bf16
    float*  a_s1 = (float*)(HB + (size_t)n * 64);        // [n*8]
    float*  a_d1 = a_s1 + (size_t)n * 8;                 // [n*8]
    float*  a_s2 = a_d1 + (size_t)n * 8;                 // [n]
    float*  a_d2 = a_s2 + n;                             // [n]
    int*    rp   = (int*)(a_d2 + n);                     // [n]
    int*    pcur = rp + n;                               // [NBUK]
    int*    boff = pcur + NBUK;                          // [NBUK]
    int*    ssrc = boff + NBUK;                          // [ET]

    const int gemm_grid = (n + 63) / 64;
    const int node_grid = (n + 3) / 4;
    const int part_grid = (ET + CH2 - 1) / CH2;

    // ---- CSR build (reused by both layers) ----
    init_pcur<<<1, NBUK, 0, stream>>>(pcur);
    partition_pairs<<<part_grid, 1024, 0, stream>>>(ei, E_, ET, pcur, pairs);
    bucket_scan<<<1, NBUK, 0, stream>>>(pcur, boff, NBUKU);
    phase2_build<<<NBUKU, 1024, 0, stream>>>(pairs, pcur, boff, rp, ssrc, n);

    // ---- layer 1 ----
    gemm_bf16out<256><<<gemm_grid, 256, 0, stream>>>(x, W1, HB, n);
    node_att_h8<<<node_grid, 256, 0, stream>>>(HB, as1w, ad1w, a_s1, a_d1, n);
    gather_h8<<<node_grid, 256, 0, stream>>>(rp, ssrc, a_s1, a_d1, HB, b1, B, n);

    // ---- layer 2 ----
    gemm_bf16out<64><<<gemm_grid, 256, 0, stream>>>(B, W2, HB, n);
    node_att_h1<<<node_grid, 256, 0, stream>>>(HB, as2w, ad2w, a_s2, a_d2, n);
    gather_h1_lsm<<<node_grid, 256, 0, stream>>>(rp, ssrc, a_s2, a_d2, HB, b2, out, n);
}

// Round 7
// 239.980 us; speedup vs baseline: 1.5166x; 1.5166x over previous
//
#include <hip/hip_runtime.h>
#include <hip/hip_bf16.h>

#define LRELU_SLOPE 0.2f
#define CH2 6144          // edges per partition block (6 per thread, 1024 threads)
#define NBUK 256          // dst buckets (512 nodes each)
#define BCAP 9728         // per-bucket capacity (mean 8704, +11 sigma)

typedef unsigned int uint;
typedef unsigned short ushort;

__device__ __forceinline__ float lrelu(float a) {
    return a > 0.f ? a : LRELU_SLOPE * a;
}
__device__ __forceinline__ ushort f2bf(float f) {   // RNE
    uint u = __float_as_uint(f);
    return (ushort)((u + 0x7FFF + ((u >> 16) & 1)) >> 16);
}
__device__ __forceinline__ float bf2f(ushort h) {
    return __uint_as_float(((uint)h) << 16);
}

// ---------------- GEMM: X[nrows,K] @ W[K,64] -> OUT[nrows,64] in bf16 ----------------
template<int K>
__global__ __launch_bounds__(256) void gemm_bf16out(
    const float* __restrict__ X, const float* __restrict__ W,
    ushort* __restrict__ OUT, int nrows)
{
    __shared__ float xs[64][33];
    __shared__ float ws[32][64];
    const int tid = threadIdx.x;
    const int block_row = blockIdx.x * 64;
    const int tx = tid & 15, ty = tid >> 4;
    float acc[4][4] = {};

    for (int k0 = 0; k0 < K; k0 += 32) {
        #pragma unroll
        for (int half = 0; half < 2; ++half) {
            int r = (tid >> 3) + 32 * half;
            int kq = (tid & 7) * 4;
            int gr = block_row + r;
            float4 v = make_float4(0.f, 0.f, 0.f, 0.f);
            if (gr < nrows) v = *(const float4*)(X + (size_t)gr * K + k0 + kq);
            xs[r][kq + 0] = v.x; xs[r][kq + 1] = v.y;
            xs[r][kq + 2] = v.z; xs[r][kq + 3] = v.w;
        }
        #pragma unroll
        for (int half = 0; half < 2; ++half) {
            int i = tid + 256 * half;
            int r = i >> 4, cq = (i & 15) << 2;
            float4 w = *(const float4*)(W + (size_t)(k0 + r) * 64 + cq);
            *(float4*)&ws[r][cq] = w;
        }
        __syncthreads();
        #pragma unroll
        for (int kk = 0; kk < 32; ++kk) {
            float4 wv = *(const float4*)&ws[kk][tx << 2];
            float xr[4];
            #pragma unroll
            for (int i = 0; i < 4; ++i) xr[i] = xs[(ty << 2) + i][kk];
            #pragma unroll
            for (int i = 0; i < 4; ++i) {
                acc[i][0] += xr[i] * wv.x; acc[i][1] += xr[i] * wv.y;
                acc[i][2] += xr[i] * wv.z; acc[i][3] += xr[i] * wv.w;
            }
        }
        __syncthreads();
    }
    #pragma unroll
    for (int i = 0; i < 4; ++i) {
        int gr = block_row + (ty << 2) + i;
        if (gr < nrows) {
            uint2 o;
            o.x = (uint)f2bf(acc[i][0]) | ((uint)f2bf(acc[i][1]) << 16);
            o.y = (uint)f2bf(acc[i][2]) | ((uint)f2bf(acc[i][3]) << 16);
            *(uint2*)(OUT + (size_t)gr * 64 + (tx << 2)) = o;
        }
    }
}

// ---------------- per-node attention logits ----------------
__global__ __launch_bounds__(256) void node_att_h8(
    const ushort* __restrict__ H, const float* __restrict__ att_s,
    const float* __restrict__ att_d,
    float* __restrict__ a_src, float* __restrict__ a_dst, int n)
{
    int node = blockIdx.x * 4 + (threadIdx.x >> 6);
    if (node >= n) return;
    int lane = threadIdx.x & 63;
    float h = bf2f(H[(size_t)node * 64 + lane]);
    float ps = h * att_s[lane];
    float pd = h * att_d[lane];
    #pragma unroll
    for (int off = 1; off < 8; off <<= 1) {
        ps += __shfl_xor(ps, off, 64);
        pd += __shfl_xor(pd, off, 64);
    }
    if ((lane & 7) == 0) {
        a_src[(size_t)node * 8 + (lane >> 3)] = ps;
        a_dst[(size_t)node * 8 + (lane >> 3)] = pd;
    }
}

__global__ __launch_bounds__(256) void node_att_h1(
    const ushort* __restrict__ H, const float* __restrict__ att_s,
    const float* __restrict__ att_d,
    float* __restrict__ a_src, float* __restrict__ a_dst, int n)
{
    int node = blockIdx.x * 4 + (threadIdx.x >> 6);
    if (node >= n) return;
    int lane = threadIdx.x & 63;
    float h = bf2f(H[(size_t)node * 64 + lane]);
    float ps = h * att_s[lane];
    float pd = h * att_d[lane];
    #pragma unroll
    for (int off = 1; off < 64; off <<= 1) {
        ps += __shfl_xor(ps, off, 64);
        pd += __shfl_xor(pd, off, 64);
    }
    if (lane == 0) { a_src[node] = ps; a_dst[node] = pd; }
}

// ---------------- init per-bucket cursors ----------------
__global__ void init_pcur(int* __restrict__ pcur)
{
    int t = threadIdx.x;
    if (t < NBUK) pcur[t] = t * BCAP;
}

// ---- phase 1: register-held partition of edges into dst buckets ----
__global__ __launch_bounds__(1024) void partition_pairs(
    const int* __restrict__ ei, int E_, int ET,
    int* __restrict__ pcur, uint* __restrict__ pairs)
{
    __shared__ int lcnt[NBUK], lsc[NBUK], lplace[NBUK], gpos[NBUK];
    const int t = threadIdx.x;
    const int base = blockIdx.x * CH2;
    const int total = min(CH2, ET - base);
    if (total <= 0) return;

    if (t < NBUK) lcnt[t] = 0;
    __syncthreads();

    uint pp[6]; int pk[6];
    #pragma unroll
    for (int i = 0; i < 6; ++i) {
        int idx = t + i * 1024;
        pk[i] = -1;
        if (idx < total) {
            int e = base + idx;
            int s, d;
            if (e < E_) { s = ei[e]; d = ei[E_ + e]; } else { s = d = e - E_; }
            pk[i] = d >> 9;
            pp[i] = (uint)s | ((uint)(d & 511) << 17);
            atomicAdd(&lcnt[pk[i]], 1);
        }
    }
    __syncthreads();

    if (t < NBUK) lsc[t] = lcnt[t];
    __syncthreads();
    for (int off = 1; off < NBUK; off <<= 1) {
        int add = 0;
        if (t < NBUK && t >= off) add = lsc[t - off];
        __syncthreads();
        if (t < NBUK) lsc[t] += add;
        __syncthreads();
    }
    if (t < NBUK) {
        int excl = lsc[t] - lcnt[t];
        lplace[t] = excl;
        int c = lcnt[t];
        gpos[t] = c ? (atomicAdd(&pcur[t], c) - excl) : 0;
    }
    __syncthreads();

    #pragma unroll
    for (int i = 0; i < 6; ++i) {
        if (pk[i] >= 0) {
            int slot = atomicAdd(&lplace[pk[i]], 1);
            pairs[gpos[pk[i]] + slot] = pp[i];
        }
    }
}

// ---- exclusive scan of bucket totals -> boff (single block) ----
__global__ __launch_bounds__(256) void bucket_scan(
    const int* __restrict__ pcur, int* __restrict__ boff, int nbuk_used)
{
    __shared__ int sm[NBUK];
    int t = threadIdx.x;
    int v = (t < nbuk_used) ? (pcur[t] - t * BCAP) : 0;
    sm[t] = v; __syncthreads();
    for (int off = 1; off < NBUK; off <<= 1) {
        int add = (t >= off) ? sm[t - off] : 0;
        __syncthreads();
        sm[t] += add;
        __syncthreads();
    }
    boff[t] = sm[t] - v;   // exclusive
}

// ---- phase 2: per-bucket histogram + scan + scatter; writes rp AND ssrc ----
__global__ __launch_bounds__(1024) void phase2_build(
    const uint* __restrict__ pairs, const int* __restrict__ pcur,
    const int* __restrict__ boff,
    int* __restrict__ rp, int* __restrict__ ssrc, int n)
{
    __shared__ int hist[512], cur[512];
    const int k = blockIdx.x;
    const int t = threadIdx.x;
    const int beg = k * BCAP;
    const int cnt = pcur[k] - beg;
    const int bbase = boff[k];
    const int dbase = k << 9;

    if (t < 512) hist[t] = 0;
    __syncthreads();

    uint pp[10];
    int m = 0;
    for (int i = t; i < cnt; i += 1024) {
        uint p = pairs[beg + i];
        pp[m++] = p;
        atomicAdd(&hist[p >> 17], 1);
    }
    __syncthreads();

    int c0 = (t < 512) ? hist[t] : 0;
    for (int off = 1; off < 512; off <<= 1) {
        int add = 0;
        if (t < 512 && t >= off) add = hist[t - off];
        __syncthreads();
        if (t < 512) hist[t] += add;
        __syncthreads();
    }
    if (t < 512) {
        int node = dbase + t;
        if (node < n) rp[node] = bbase + hist[t];
        cur[t] = hist[t] - c0;
    }
    __syncthreads();

    m = 0;
    for (int i = t; i < cnt; i += 1024) {
        uint p = pp[m++];
        int j = p >> 17;
        int pos = bbase + atomicAdd(&cur[j], 1);
        ssrc[pos] = (int)(p & 0x1FFFF);
    }
}

// ---- pull-gather layer 1 (8 heads): half-wave (32 lanes) per node, 2 ch/lane ----
// lane hl owns channels (2hl, 2hl+1), both in head q = hl>>2.
// Every lane's dsum accumulates the full denom for head q (identical copies).
__global__ __launch_bounds__(256) void gather_h8(
    const int* __restrict__ rp, const int* __restrict__ ssrc,
    const float* __restrict__ a_src, const float* __restrict__ a_dst,
    const ushort* __restrict__ HB, const float* __restrict__ bias,
    float* __restrict__ B, int n)
{
    int node = blockIdx.x * 8 + (threadIdx.x >> 5);
    if (node >= n) return;
    int hl = threadIdx.x & 31;
    int q = hl >> 2;
    int end = rp[node];
    int start = node ? rp[node - 1] : 0;
    float adh = a_dst[(size_t)node * 8 + q];
    float accx = 0.f, accy = 0.f, dsum = 0.f;

    for (int i0 = start; i0 < end; i0 += 32) {
        int cnt = min(32, end - i0);
        int sv = (hl < cnt) ? ssrc[i0 + hl] : 0;
        int j = 0;
        for (; j + 4 <= cnt; j += 4) {
            #pragma unroll
            for (int k = 0; k < 4; ++k) {
                int sj = __shfl(sv, j + k, 32);
                float a = a_src[(size_t)sj * 8 + q] + adh;
                a = a > 0.f ? a : LRELU_SLOPE * a;
                float e = __expf(a);
                uint hv = *(const uint*)(HB + (size_t)sj * 64 + hl * 2);
                dsum += e;
                accx += e * bf2f((ushort)(hv & 0xffff));
                accy += e * bf2f((ushort)(hv >> 16));
            }
        }
        for (; j < cnt; ++j) {
            int sj = __shfl(sv, j, 32);
            float a = a_src[(size_t)sj * 8 + q] + adh;
            a = a > 0.f ? a : LRELU_SLOPE * a;
            float e = __expf(a);
            uint hv = *(const uint*)(HB + (size_t)sj * 64 + hl * 2);
            dsum += e;
            accx += e * bf2f((ushort)(hv & 0xffff));
            accy += e * bf2f((ushort)(hv >> 16));
        }
    }
    float inv = 1.f / (dsum + 1e-16f);
    float2 bb = *(const float2*)(bias + hl * 2);
    float vx = accx * inv + bb.x;
    float vy = accy * inv + bb.y;
    vx = vx > 0.f ? vx : expm1f(vx);
    vy = vy > 0.f ? vy : expm1f(vy);
    *(float2*)(B + (size_t)node * 64 + hl * 2) = make_float2(vx, vy);
}

// ---- pull-gather layer 2 (1 head): half-wave per node, 2 ch/lane + lsm ----
__global__ __launch_bounds__(256) void gather_h1_lsm(
    const int* __restrict__ rp, const int* __restrict__ ssrc,
    const float* __restrict__ a_src, const float* __restrict__ a_dst,
    const ushort* __restrict__ HB, const float* __restrict__ bias,
    float* __restrict__ OUT, int n)
{
    int node = blockIdx.x * 8 + (threadIdx.x >> 5);
    if (node >= n) return;
    int hl = threadIdx.x & 31;
    int end = rp[node];
    int start = node ? rp[node - 1] : 0;
    float ad = a_dst[node];
    float accx = 0.f, accy = 0.f, dsum = 0.f;

    for (int i0 = start; i0 < end; i0 += 32) {
        int cnt = min(32, end - i0);
        int sv = (hl < cnt) ? ssrc[i0 + hl] : 0;
        int j = 0;
        for (; j + 4 <= cnt; j += 4) {
            #pragma unroll
            for (int k = 0; k < 4; ++k) {
                int sj = __shfl(sv, j + k, 32);
                float a = a_src[sj] + ad;
                a = a > 0.f ? a : LRELU_SLOPE * a;
                float e = __expf(a);
                uint hv = *(const uint*)(HB + (size_t)sj * 64 + hl * 2);
                dsum += e;
                accx += e * bf2f((ushort)(hv & 0xffff));
                accy += e * bf2f((ushort)(hv >> 16));
            }
        }
        for (; j < cnt; ++j) {
            int sj = __shfl(sv, j, 32);
            float a = a_src[sj] + ad;
            a = a > 0.f ? a : LRELU_SLOPE * a;
            float e = __expf(a);
            uint hv = *(const uint*)(HB + (size_t)sj * 64 + hl * 2);
            dsum += e;
            accx += e * bf2f((ushort)(hv & 0xffff));
            accy += e * bf2f((ushort)(hv >> 16));
        }
    }
    float inv = 1.f / (dsum + 1e-16f);
    float2 bb = *(const float2*)(bias + hl * 2);
    float vx = accx * inv + bb.x;
    float vy = accy * inv + bb.y;

    float m = fmaxf(vx, vy);
    #pragma unroll
    for (int off = 1; off < 32; off <<= 1) m = fmaxf(m, __shfl_xor(m, off, 32));
    float s = __expf(vx - m) + __expf(vy - m);
    #pragma unroll
    for (int off = 1; off < 32; off <<= 1) s += __shfl_xor(s, off, 32);
    float lse = m + __logf(s);
    *(float2*)(OUT + (size_t)node * 64 + hl * 2) = make_float2(vx - lse, vy - lse);
}

extern "C" void kernel_launch(void* const* d_in, const int* in_sizes, int n_in,
                              void* d_out, int out_size, void* d_ws, size_t ws_size,
                              hipStream_t stream)
{
    const float* x    = (const float*)d_in[0];
    const int*   ei   = (const int*)d_in[1];
    const float* W1   = (const float*)d_in[2];
    const float* as1w = (const float*)d_in[3];
    const float* ad1w = (const float*)d_in[4];
    const float* b1   = (const float*)d_in[5];
    const float* W2   = (const float*)d_in[6];
    const float* as2w = (const float*)d_in[7];
    const float* ad2w = (const float*)d_in[8];
    const float* b2   = (const float*)d_in[9];
    float* out = (float*)d_out;

    const int n  = in_sizes[0] / 256;     // 100000
    const int E_ = in_sizes[1] / 2;       // 1600000
    const int ET = E_ + n;
    const int NBUKU = (n + 511) >> 9;     // 196 used buckets

    char* wsb = (char*)d_ws;
    float*  B    = (float*)wsb;                          // [n*64] f32 (aliases pairs)
    uint*   pairs= (uint*)wsb;                           // [NBUK*BCAP] (build-time only)
    ushort* HB   = (ushort*)(B + (size_t)n * 64);        // [n*64] bf16
    float*  a_s1 = (float*)(HB + (size_t)n * 64);        // [n*8]
    float*  a_d1 = a_s1 + (size_t)n * 8;                 // [n*8]
    float*  a_s2 = a_d1 + (size_t)n * 8;                 // [n]
    float*  a_d2 = a_s2 + n;                             // [n]
    int*    rp   = (int*)(a_d2 + n);                     // [n]
    int*    pcur = rp + n;                               // [NBUK]
    int*    boff = pcur + NBUK;                          // [NBUK]
    int*    ssrc = boff + NBUK;                          // [ET]

    const int gemm_grid = (n + 63) / 64;
    const int natt_grid = (n + 3) / 4;
    const int gath_grid = (n + 7) / 8;
    const int part_grid = (ET + CH2 - 1) / CH2;

    // ---- CSR build (reused by both layers) ----
    init_pcur<<<1, NBUK, 0, stream>>>(pcur);
    partition_pairs<<<part_grid, 1024, 0, stream>>>(ei, E_, ET, pcur, pairs);
    bucket_scan<<<1, NBUK, 0, stream>>>(pcur, boff, NBUKU);
    phase2_build<<<NBUKU, 1024, 0, stream>>>(pairs, pcur, boff, rp, ssrc, n);

    // ---- layer 1 ----
    gemm_bf16out<256><<<gemm_grid, 256, 0, stream>>>(x, W1, HB, n);
    node_att_h8<<<natt_grid, 256, 0, stream>>>(HB, as1w, ad1w, a_s1, a_d1, n);
    gather_h8<<<gath_grid, 256, 0, stream>>>(rp, ssrc, a_s1, a_d1, HB, b1, B, n);

    // ---- layer 2 ----
    gemm_bf16out<64><<<gemm_grid, 256, 0, stream>>>(B, W2, HB, n);
    node_att_h1<<<natt_grid, 256, 0, stream>>>(HB, as2w, ad2w, a_s2, a_d2, n);
    gather_h1_lsm<<<gath_grid, 256, 0, stream>>>(rp, ssrc, a_s2, a_d2, HB, b2, out, n);
}

// Round 8
// 198.065 us; speedup vs baseline: 1.8376x; 1.2116x over previous
//
#include <hip/hip_runtime.h>
#include <hip/hip_bf16.h>

#define LRELU_SLOPE 0.2f
#define CH2 6144          // edges per partition block (6 per thread, 1024 threads)
#define NBUK 256          // dst buckets (512 nodes each)
#define BCAP 9728         // per-bucket capacity (mean 8704, +11 sigma)

typedef unsigned int uint;
typedef unsigned short ushort;
typedef short bt8 __attribute__((ext_vector_type(8)));   // 8 bf16 (4 VGPRs)
typedef float fx4 __attribute__((ext_vector_type(4)));   // MFMA accumulator

__device__ __forceinline__ float lrelu(float a) {
    return a > 0.f ? a : LRELU_SLOPE * a;
}
__device__ __forceinline__ ushort f2bf(float f) {   // RNE
    uint u = __float_as_uint(f);
    return (ushort)((u + 0x7FFF + ((u >> 16) & 1)) >> 16);
}
__device__ __forceinline__ float bf2f(ushort h) {
    return __uint_as_float(((uint)h) << 16);
}

// ---- prep: W[K][64] f32 -> WT[64][K] bf16 (both layers, one tiny kernel) ----
__global__ __launch_bounds__(256) void prep_wt(
    const float* __restrict__ W1, const float* __restrict__ W2,
    ushort* __restrict__ WT1, ushort* __restrict__ WT2)
{
    int idx = blockIdx.x * 256 + threadIdx.x;
    if (idx < 64 * 256) {
        int c = idx >> 8, k = idx & 255;
        WT1[idx] = f2bf(W1[k * 64 + c]);
    }
    int i2 = idx - 64 * 256;
    if (i2 >= 0 && i2 < 64 * 64) {
        int c = i2 >> 6, k = i2 & 63;
        WT2[i2] = f2bf(W2[k * 64 + c]);
    }
}

// ---- MFMA GEMM: X[nrows,K] @ W[K,64] -> OUT[nrows,64] bf16 ----
// block = 64 rows x 64 cols, 4 waves; wave w owns rows 16w..16w+15.
// INF32: X is f32 (converted to bf16 during staging); else X is bf16.
template<int K, bool INF32>
__global__ __launch_bounds__(256) void gemm_mfma(
    const void* __restrict__ Xv, const ushort* __restrict__ WT,
    ushort* __restrict__ OUT, int nrows)
{
    constexpr int LDW = K + 8;            // padded W^T stride (bank-conflict)
    __shared__ ushort wt_l[64 * LDW];
    __shared__ ushort a_l[64 * 40];       // 64 x 32, stride 40
    const int t = threadIdx.x;
    const int base = blockIdx.x * 64;

    // load W^T (bf16) into LDS once
    for (int idx = t * 8; idx < 64 * K; idx += 256 * 8) {
        int r = idx / K, c = idx % K;
        *(uint4*)&wt_l[r * LDW + c] = *(const uint4*)&WT[idx];
    }
    __syncthreads();

    const int w = t >> 6, l = t & 63;
    const int frow = l & 15;              // fragment row/col index
    const int kof = (l >> 4) * 8;         // fragment k offset
    fx4 acc[4] = {};

    for (int k0 = 0; k0 < K; k0 += 32) {
        if constexpr (INF32) {
            const float* X = (const float*)Xv;
            #pragma unroll
            for (int half = 0; half < 2; ++half) {
                int r = (t >> 3) + 32 * half;
                int kq = (t & 7) * 4;
                int gr = base + r;
                float4 v = make_float4(0.f, 0.f, 0.f, 0.f);
                if (gr < nrows) v = *(const float4*)(X + (size_t)gr * K + k0 + kq);
                ushort4 o;
                o.x = f2bf(v.x); o.y = f2bf(v.y); o.z = f2bf(v.z); o.w = f2bf(v.w);
                *(ushort4*)&a_l[r * 40 + kq] = o;
            }
        } else {
            const ushort* X = (const ushort*)Xv;
            int r = t >> 2;
            int kq = (t & 3) * 8;
            int gr = base + r;
            uint4 v = make_uint4(0, 0, 0, 0);
            if (gr < nrows) v = *(const uint4*)(X + (size_t)gr * K + k0 + kq);
            *(uint4*)&a_l[r * 40 + kq] = v;
        }
        __syncthreads();
        bt8 af = *(const bt8*)&a_l[(16 * w + frow) * 40 + kof];
        #pragma unroll
        for (int g = 0; g < 4; ++g) {
            bt8 bf = *(const bt8*)&wt_l[(16 * g + frow) * LDW + k0 + kof];
            acc[g] = __builtin_amdgcn_mfma_f32_16x16x32_bf16(af, bf, acc[g], 0, 0, 0);
        }
        __syncthreads();
    }

    // epilogue: C/D layout col=lane&15, row=(lane>>4)*4+reg
    const int orow0 = base + 16 * w + (l >> 4) * 4;
    const int ocol = l & 15;
    #pragma unroll
    for (int g = 0; g < 4; ++g) {
        #pragma unroll
        for (int r4 = 0; r4 < 4; ++r4) {
            int gr = orow0 + r4;
            if (gr < nrows) OUT[(size_t)gr * 64 + 16 * g + ocol] = f2bf(acc[g][r4]);
        }
    }
}

// ---------------- per-node attention logits ----------------
__global__ __launch_bounds__(256) void node_att_h8(
    const ushort* __restrict__ H, const float* __restrict__ att_s,
    const float* __restrict__ att_d,
    float* __restrict__ a_src, float* __restrict__ a_dst, int n)
{
    int node = blockIdx.x * 4 + (threadIdx.x >> 6);
    if (node >= n) return;
    int lane = threadIdx.x & 63;
    float h = bf2f(H[(size_t)node * 64 + lane]);
    float ps = h * att_s[lane];
    float pd = h * att_d[lane];
    #pragma unroll
    for (int off = 1; off < 8; off <<= 1) {
        ps += __shfl_xor(ps, off, 64);
        pd += __shfl_xor(pd, off, 64);
    }
    if ((lane & 7) == 0) {
        a_src[(size_t)node * 8 + (lane >> 3)] = ps;
        a_dst[(size_t)node * 8 + (lane >> 3)] = pd;
    }
}

__global__ __launch_bounds__(256) void node_att_h1(
    const ushort* __restrict__ H, const float* __restrict__ att_s,
    const float* __restrict__ att_d,
    float* __restrict__ a_src, float* __restrict__ a_dst, int n)
{
    int node = blockIdx.x * 4 + (threadIdx.x >> 6);
    if (node >= n) return;
    int lane = threadIdx.x & 63;
    float h = bf2f(H[(size_t)node * 64 + lane]);
    float ps = h * att_s[lane];
    float pd = h * att_d[lane];
    #pragma unroll
    for (int off = 1; off < 64; off <<= 1) {
        ps += __shfl_xor(ps, off, 64);
        pd += __shfl_xor(pd, off, 64);
    }
    if (lane == 0) { a_src[node] = ps; a_dst[node] = pd; }
}

// ---------------- init per-bucket cursors ----------------
__global__ void init_pcur(int* __restrict__ pcur)
{
    int t = threadIdx.x;
    if (t < NBUK) pcur[t] = t * BCAP;
}

// ---- phase 1: register-held partition of edges into dst buckets ----
__global__ __launch_bounds__(1024) void partition_pairs(
    const int* __restrict__ ei, int E_, int ET,
    int* __restrict__ pcur, uint* __restrict__ pairs)
{
    __shared__ int lcnt[NBUK], lsc[NBUK], lplace[NBUK], gpos[NBUK];
    const int t = threadIdx.x;
    const int base = blockIdx.x * CH2;
    const int total = min(CH2, ET - base);
    if (total <= 0) return;

    if (t < NBUK) lcnt[t] = 0;
    __syncthreads();

    uint pp[6]; int pk[6];
    #pragma unroll
    for (int i = 0; i < 6; ++i) {
        int idx = t + i * 1024;
        pk[i] = -1;
        if (idx < total) {
            int e = base + idx;
            int s, d;
            if (e < E_) { s = ei[e]; d = ei[E_ + e]; } else { s = d = e - E_; }
            pk[i] = d >> 9;
            pp[i] = (uint)s | ((uint)(d & 511) << 17);
            atomicAdd(&lcnt[pk[i]], 1);
        }
    }
    __syncthreads();

    if (t < NBUK) lsc[t] = lcnt[t];
    __syncthreads();
    for (int off = 1; off < NBUK; off <<= 1) {
        int add = 0;
        if (t < NBUK && t >= off) add = lsc[t - off];
        __syncthreads();
        if (t < NBUK) lsc[t] += add;
        __syncthreads();
    }
    if (t < NBUK) {
        int excl = lsc[t] - lcnt[t];
        lplace[t] = excl;
        int c = lcnt[t];
        gpos[t] = c ? (atomicAdd(&pcur[t], c) - excl) : 0;
    }
    __syncthreads();

    #pragma unroll
    for (int i = 0; i < 6; ++i) {
        if (pk[i] >= 0) {
            int slot = atomicAdd(&lplace[pk[i]], 1);
            pairs[gpos[pk[i]] + slot] = pp[i];
        }
    }
}

// ---- exclusive scan of bucket totals -> boff (single block) ----
__global__ __launch_bounds__(256) void bucket_scan(
    const int* __restrict__ pcur, int* __restrict__ boff, int nbuk_used)
{
    __shared__ int sm[NBUK];
    int t = threadIdx.x;
    int v = (t < nbuk_used) ? (pcur[t] - t * BCAP) : 0;
    sm[t] = v; __syncthreads();
    for (int off = 1; off < NBUK; off <<= 1) {
        int add = (t >= off) ? sm[t - off] : 0;
        __syncthreads();
        sm[t] += add;
        __syncthreads();
    }
    boff[t] = sm[t] - v;   // exclusive
}

// ---- phase 2: per-bucket histogram + scan + scatter; writes rp AND ssrc ----
__global__ __launch_bounds__(1024) void phase2_build(
    const uint* __restrict__ pairs, const int* __restrict__ pcur,
    const int* __restrict__ boff,
    int* __restrict__ rp, int* __restrict__ ssrc, int n)
{
    __shared__ int hist[512], cur[512];
    const int k = blockIdx.x;
    const int t = threadIdx.x;
    const int beg = k * BCAP;
    const int cnt = pcur[k] - beg;
    const int bbase = boff[k];
    const int dbase = k << 9;

    if (t < 512) hist[t] = 0;
    __syncthreads();

    uint pp[10];
    int m = 0;
    for (int i = t; i < cnt; i += 1024) {
        uint p = pairs[beg + i];
        pp[m++] = p;
        atomicAdd(&hist[p >> 17], 1);
    }
    __syncthreads();

    int c0 = (t < 512) ? hist[t] : 0;
    for (int off = 1; off < 512; off <<= 1) {
        int add = 0;
        if (t < 512 && t >= off) add = hist[t - off];
        __syncthreads();
        if (t < 512) hist[t] += add;
        __syncthreads();
    }
    if (t < 512) {
        int node = dbase + t;
        if (node < n) rp[node] = bbase + hist[t];
        cur[t] = hist[t] - c0;
    }
    __syncthreads();

    m = 0;
    for (int i = t; i < cnt; i += 1024) {
        uint p = pp[m++];
        int j = p >> 17;
        int pos = bbase + atomicAdd(&cur[j], 1);
        ssrc[pos] = (int)(p & 0x1FFFF);
    }
}

// ---- pull-gather layer 1 (8 heads): half-wave per node, 2 ch/lane; bf16 out ----
__global__ __launch_bounds__(256) void gather_h8(
    const int* __restrict__ rp, const int* __restrict__ ssrc,
    const float* __restrict__ a_src, const float* __restrict__ a_dst,
    const ushort* __restrict__ HB, const float* __restrict__ bias,
    ushort* __restrict__ HACT, int n)
{
    int node = blockIdx.x * 8 + (threadIdx.x >> 5);
    if (node >= n) return;
    int hl = threadIdx.x & 31;
    int q = hl >> 2;
    int end = rp[node];
    int start = node ? rp[node - 1] : 0;
    float adh = a_dst[(size_t)node * 8 + q];
    float accx = 0.f, accy = 0.f, dsum = 0.f;

    for (int i0 = start; i0 < end; i0 += 32) {
        int cnt = min(32, end - i0);
        int sv = (hl < cnt) ? ssrc[i0 + hl] : 0;
        int j = 0;
        for (; j + 4 <= cnt; j += 4) {
            #pragma unroll
            for (int k = 0; k < 4; ++k) {
                int sj = __shfl(sv, j + k, 32);
                float a = a_src[(size_t)sj * 8 + q] + adh;
                a = a > 0.f ? a : LRELU_SLOPE * a;
                float e = __expf(a);
                uint hv = *(const uint*)(HB + (size_t)sj * 64 + hl * 2);
                dsum += e;
                accx += e * bf2f((ushort)(hv & 0xffff));
                accy += e * bf2f((ushort)(hv >> 16));
            }
        }
        for (; j < cnt; ++j) {
            int sj = __shfl(sv, j, 32);
            float a = a_src[(size_t)sj * 8 + q] + adh;
            a = a > 0.f ? a : LRELU_SLOPE * a;
            float e = __expf(a);
            uint hv = *(const uint*)(HB + (size_t)sj * 64 + hl * 2);
            dsum += e;
            accx += e * bf2f((ushort)(hv & 0xffff));
            accy += e * bf2f((ushort)(hv >> 16));
        }
    }
    float inv = 1.f / (dsum + 1e-16f);
    float2 bb = *(const float2*)(bias + hl * 2);
    float vx = accx * inv + bb.x;
    float vy = accy * inv + bb.y;
    vx = vx > 0.f ? vx : expm1f(vx);
    vy = vy > 0.f ? vy : expm1f(vy);
    uint pv = (uint)f2bf(vx) | ((uint)f2bf(vy) << 16);
    *(uint*)(HACT + (size_t)node * 64 + hl * 2) = pv;
}

// ---- pull-gather layer 2 (1 head): half-wave per node, 2 ch/lane + lsm ----
__global__ __launch_bounds__(256) void gather_h1_lsm(
    const int* __restrict__ rp, const int* __restrict__ ssrc,
    const float* __restrict__ a_src, const float* __restrict__ a_dst,
    const ushort* __restrict__ HB, const float* __restrict__ bias,
    float* __restrict__ OUT, int n)
{
    int node = blockIdx.x * 8 + (threadIdx.x >> 5);
    if (node >= n) return;
    int hl = threadIdx.x & 31;
    int end = rp[node];
    int start = node ? rp[node - 1] : 0;
    float ad = a_dst[node];
    float accx = 0.f, accy = 0.f, dsum = 0.f;

    for (int i0 = start; i0 < end; i0 += 32) {
        int cnt = min(32, end - i0);
        int sv = (hl < cnt) ? ssrc[i0 + hl] : 0;
        int j = 0;
        for (; j + 4 <= cnt; j += 4) {
            #pragma unroll
            for (int k = 0; k < 4; ++k) {
                int sj = __shfl(sv, j + k, 32);
                float a = a_src[sj] + ad;
                a = a > 0.f ? a : LRELU_SLOPE * a;
                float e = __expf(a);
                uint hv = *(const uint*)(HB + (size_t)sj * 64 + hl * 2);
                dsum += e;
                accx += e * bf2f((ushort)(hv & 0xffff));
                accy += e * bf2f((ushort)(hv >> 16));
            }
        }
        for (; j < cnt; ++j) {
            int sj = __shfl(sv, j, 32);
            float a = a_src[sj] + ad;
            a = a > 0.f ? a : LRELU_SLOPE * a;
            float e = __expf(a);
            uint hv = *(const uint*)(HB + (size_t)sj * 64 + hl * 2);
            dsum += e;
            accx += e * bf2f((ushort)(hv & 0xffff));
            accy += e * bf2f((ushort)(hv >> 16));
        }
    }
    float inv = 1.f / (dsum + 1e-16f);
    float2 bb = *(const float2*)(bias + hl * 2);
    float vx = accx * inv + bb.x;
    float vy = accy * inv + bb.y;

    float m = fmaxf(vx, vy);
    #pragma unroll
    for (int off = 1; off < 32; off <<= 1) m = fmaxf(m, __shfl_xor(m, off, 32));
    float s = __expf(vx - m) + __expf(vy - m);
    #pragma unroll
    for (int off = 1; off < 32; off <<= 1) s += __shfl_xor(s, off, 32);
    float lse = m + __logf(s);
    *(float2*)(OUT + (size_t)node * 64 + hl * 2) = make_float2(vx - lse, vy - lse);
}

extern "C" void kernel_launch(void* const* d_in, const int* in_sizes, int n_in,
                              void* d_out, int out_size, void* d_ws, size_t ws_size,
                              hipStream_t stream)
{
    const float* x    = (const float*)d_in[0];
    const int*   ei   = (const int*)d_in[1];
    const float* W1   = (const float*)d_in[2];
    const float* as1w = (const float*)d_in[3];
    const float* ad1w = (const float*)d_in[4];
    const float* b1   = (const float*)d_in[5];
    const float* W2   = (const float*)d_in[6];
    const float* as2w = (const float*)d_in[7];
    const float* ad2w = (const float*)d_in[8];
    const float* b2   = (const float*)d_in[9];
    float* out = (float*)d_out;

    const int n  = in_sizes[0] / 256;     // 100000
    const int E_ = in_sizes[1] / 2;       // 1600000
    const int ET = E_ + n;
    const int NBUKU = (n + 511) >> 9;     // 196 used buckets

    char* wsb = (char*)d_ws;
    ushort* HACT = (ushort*)wsb;                         // [n*64] bf16 (aliases pairs)
    uint*   pairs= (uint*)wsb;                           // [NBUK*BCAP] build-time only
    ushort* HB   = HACT + (size_t)n * 64;                // [n*64] bf16
    float*  a_s1 = (float*)(HB + (size_t)n * 64);        // [n*8]
    float*  a_d1 = a_s1 + (size_t)n * 8;                 // [n*8]
    float*  a_s2 = a_d1 + (size_t)n * 8;                 // [n]
    float*  a_d2 = a_s2 + n;                             // [n]
    int*    rp   = (int*)(a_d2 + n);                     // [n]
    int*    pcur = rp + n;                               // [NBUK]
    int*    boff = pcur + NBUK;                          // [NBUK]
    int*    ssrc = boff + NBUK;                          // [ET]
    ushort* WT1  = (ushort*)(ssrc + ET);                 // [64*256]
    ushort* WT2  = WT1 + 64 * 256;                       // [64*64]

    const int gemm_grid = (n + 63) / 64;
    const int natt_grid = (n + 3) / 4;
    const int gath_grid = (n + 7) / 8;
    const int part_grid = (ET + CH2 - 1) / CH2;

    // ---- weight prep + CSR build (reused by both layers) ----
    prep_wt<<<80, 256, 0, stream>>>(W1, W2, WT1, WT2);
    init_pcur<<<1, NBUK, 0, stream>>>(pcur);
    partition_pairs<<<part_grid, 1024, 0, stream>>>(ei, E_, ET, pcur, pairs);
    bucket_scan<<<1, NBUK, 0, stream>>>(pcur, boff, NBUKU);
    phase2_build<<<NBUKU, 1024, 0, stream>>>(pairs, pcur, boff, rp, ssrc, n);

    // ---- layer 1 ----
    gemm_mfma<256, true><<<gemm_grid, 256, 0, stream>>>(x, WT1, HB, n);
    node_att_h8<<<natt_grid, 256, 0, stream>>>(HB, as1w, ad1w, a_s1, a_d1, n);
    gather_h8<<<gath_grid, 256, 0, stream>>>(rp, ssrc, a_s1, a_d1, HB, b1, HACT, n);

    // ---- layer 2 ----
    gemm_mfma<64, false><<<gemm_grid, 256, 0, stream>>>(HACT, WT2, HB, n);
    node_att_h1<<<natt_grid, 256, 0, stream>>>(HB, as2w, ad2w, a_s2, a_d2, n);
    gather_h1_lsm<<<gath_grid, 256, 0, stream>>>(rp, ssrc, a_s2, a_d2, HB, b2, out, n);
}

// Round 9
// 189.606 us; speedup vs baseline: 1.9195x; 1.0446x over previous
//
#include <hip/hip_runtime.h>
#include <hip/hip_bf16.h>

#define LRELU_SLOPE 0.2f
#define CH2 6144          // edges per partition block (6 per thread, 1024 threads)
#define NBUK 256          // dst buckets (512 nodes each)
#define BCAP 9728         // per-bucket capacity (mean 8704, +11 sigma)

typedef unsigned int uint;
typedef unsigned short ushort;
typedef short bt8 __attribute__((ext_vector_type(8)));   // 8 bf16 (4 VGPRs)
typedef float fx4 __attribute__((ext_vector_type(4)));   // MFMA accumulator

__device__ __forceinline__ float lrelu(float a) {
    return a > 0.f ? a : LRELU_SLOPE * a;
}
__device__ __forceinline__ ushort f2bf(float f) {   // RNE
    uint u = __float_as_uint(f);
    return (ushort)((u + 0x7FFF + ((u >> 16) & 1)) >> 16);
}
__device__ __forceinline__ float bf2f(ushort h) {
    return __uint_as_float(((uint)h) << 16);
}

// ---- prep: W[K][64] f32 -> WT[64][K] bf16 (both layers, one tiny kernel) ----
__global__ __launch_bounds__(256) void prep_wt(
    const float* __restrict__ W1, const float* __restrict__ W2,
    ushort* __restrict__ WT1, ushort* __restrict__ WT2)
{
    int idx = blockIdx.x * 256 + threadIdx.x;
    if (idx < 64 * 256) {
        int c = idx >> 8, k = idx & 255;
        WT1[idx] = f2bf(W1[k * 64 + c]);
    }
    int i2 = idx - 64 * 256;
    if (i2 >= 0 && i2 < 64 * 64) {
        int c = i2 >> 6, k = i2 & 63;
        WT2[i2] = f2bf(W2[k * 64 + c]);
    }
}

// ---- MFMA GEMM: X[nrows,K] @ W[K,64] -> OUT[nrows,64] bf16 ----
template<int K, bool INF32>
__global__ __launch_bounds__(256) void gemm_mfma(
    const void* __restrict__ Xv, const ushort* __restrict__ WT,
    ushort* __restrict__ OUT, int nrows)
{
    constexpr int LDW = K + 8;            // padded W^T stride (bank-conflict)
    __shared__ ushort wt_l[64 * LDW];
    __shared__ ushort a_l[64 * 40];       // 64 x 32, stride 40
    const int t = threadIdx.x;
    const int base = blockIdx.x * 64;

    for (int idx = t * 8; idx < 64 * K; idx += 256 * 8) {
        int r = idx / K, c = idx % K;
        *(uint4*)&wt_l[r * LDW + c] = *(const uint4*)&WT[idx];
    }
    __syncthreads();

    const int w = t >> 6, l = t & 63;
    const int frow = l & 15;
    const int kof = (l >> 4) * 8;
    fx4 acc[4] = {};

    for (int k0 = 0; k0 < K; k0 += 32) {
        if constexpr (INF32) {
            const float* X = (const float*)Xv;
            #pragma unroll
            for (int half = 0; half < 2; ++half) {
                int r = (t >> 3) + 32 * half;
                int kq = (t & 7) * 4;
                int gr = base + r;
                float4 v = make_float4(0.f, 0.f, 0.f, 0.f);
                if (gr < nrows) v = *(const float4*)(X + (size_t)gr * K + k0 + kq);
                ushort4 o;
                o.x = f2bf(v.x); o.y = f2bf(v.y); o.z = f2bf(v.z); o.w = f2bf(v.w);
                *(ushort4*)&a_l[r * 40 + kq] = o;
            }
        } else {
            const ushort* X = (const ushort*)Xv;
            int r = t >> 2;
            int kq = (t & 3) * 8;
            int gr = base + r;
            uint4 v = make_uint4(0, 0, 0, 0);
            if (gr < nrows) v = *(const uint4*)(X + (size_t)gr * K + k0 + kq);
            *(uint4*)&a_l[r * 40 + kq] = v;
        }
        __syncthreads();
        bt8 af = *(const bt8*)&a_l[(16 * w + frow) * 40 + kof];
        #pragma unroll
        for (int g = 0; g < 4; ++g) {
            bt8 bf = *(const bt8*)&wt_l[(16 * g + frow) * LDW + k0 + kof];
            acc[g] = __builtin_amdgcn_mfma_f32_16x16x32_bf16(af, bf, acc[g], 0, 0, 0);
        }
        __syncthreads();
    }

    const int orow0 = base + 16 * w + (l >> 4) * 4;
    const int ocol = l & 15;
    #pragma unroll
    for (int g = 0; g < 4; ++g) {
        #pragma unroll
        for (int r4 = 0; r4 < 4; ++r4) {
            int gr = orow0 + r4;
            if (gr < nrows) OUT[(size_t)gr * 64 + 16 * g + ocol] = f2bf(acc[g][r4]);
        }
    }
}

// ---------------- per-node attention logits ----------------
__global__ __launch_bounds__(256) void node_att_h8(
    const ushort* __restrict__ H, const float* __restrict__ att_s,
    const float* __restrict__ att_d,
    float* __restrict__ a_src, float* __restrict__ a_dst, int n)
{
    int node = blockIdx.x * 4 + (threadIdx.x >> 6);
    if (node >= n) return;
    int lane = threadIdx.x & 63;
    float h = bf2f(H[(size_t)node * 64 + lane]);
    float ps = h * att_s[lane];
    float pd = h * att_d[lane];
    #pragma unroll
    for (int off = 1; off < 8; off <<= 1) {
        ps += __shfl_xor(ps, off, 64);
        pd += __shfl_xor(pd, off, 64);
    }
    if ((lane & 7) == 0) {
        a_src[(size_t)node * 8 + (lane >> 3)] = ps;
        a_dst[(size_t)node * 8 + (lane >> 3)] = pd;
    }
}

__global__ __launch_bounds__(256) void node_att_h1(
    const ushort* __restrict__ H, const float* __restrict__ att_s,
    const float* __restrict__ att_d,
    float* __restrict__ a_src, float* __restrict__ a_dst, int n)
{
    int node = blockIdx.x * 4 + (threadIdx.x >> 6);
    if (node >= n) return;
    int lane = threadIdx.x & 63;
    float h = bf2f(H[(size_t)node * 64 + lane]);
    float ps = h * att_s[lane];
    float pd = h * att_d[lane];
    #pragma unroll
    for (int off = 1; off < 64; off <<= 1) {
        ps += __shfl_xor(ps, off, 64);
        pd += __shfl_xor(pd, off, 64);
    }
    if (lane == 0) { a_src[node] = ps; a_dst[node] = pd; }
}

// ---------------- init per-bucket cursors ----------------
__global__ void init_pcur(int* __restrict__ pcur)
{
    int t = threadIdx.x;
    if (t < NBUK) pcur[t] = t * BCAP;
}

// ---- phase 1: register-held partition of edges into dst buckets ----
__global__ __launch_bounds__(1024) void partition_pairs(
    const int* __restrict__ ei, int E_, int ET,
    int* __restrict__ pcur, uint* __restrict__ pairs)
{
    __shared__ int lcnt[NBUK], lsc[NBUK], lplace[NBUK], gpos[NBUK];
    const int t = threadIdx.x;
    const int base = blockIdx.x * CH2;
    const int total = min(CH2, ET - base);
    if (total <= 0) return;

    if (t < NBUK) lcnt[t] = 0;
    __syncthreads();

    uint pp[6]; int pk[6];
    #pragma unroll
    for (int i = 0; i < 6; ++i) {
        int idx = t + i * 1024;
        pk[i] = -1;
        if (idx < total) {
            int e = base + idx;
            int s, d;
            if (e < E_) { s = ei[e]; d = ei[E_ + e]; } else { s = d = e - E_; }
            pk[i] = d >> 9;
            pp[i] = (uint)s | ((uint)(d & 511) << 17);
            atomicAdd(&lcnt[pk[i]], 1);
        }
    }
    __syncthreads();

    if (t < NBUK) lsc[t] = lcnt[t];
    __syncthreads();
    for (int off = 1; off < NBUK; off <<= 1) {
        int add = 0;
        if (t < NBUK && t >= off) add = lsc[t - off];
        __syncthreads();
        if (t < NBUK) lsc[t] += add;
        __syncthreads();
    }
    if (t < NBUK) {
        int excl = lsc[t] - lcnt[t];
        lplace[t] = excl;
        int c = lcnt[t];
        gpos[t] = c ? (atomicAdd(&pcur[t], c) - excl) : 0;
    }
    __syncthreads();

    #pragma unroll
    for (int i = 0; i < 6; ++i) {
        if (pk[i] >= 0) {
            int slot = atomicAdd(&lplace[pk[i]], 1);
            pairs[gpos[pk[i]] + slot] = pp[i];
        }
    }
}

// ---- exclusive scan of bucket totals -> boff (single block) ----
__global__ __launch_bounds__(256) void bucket_scan(
    const int* __restrict__ pcur, int* __restrict__ boff, int nbuk_used)
{
    __shared__ int sm[NBUK];
    int t = threadIdx.x;
    int v = (t < nbuk_used) ? (pcur[t] - t * BCAP) : 0;
    sm[t] = v; __syncthreads();
    for (int off = 1; off < NBUK; off <<= 1) {
        int add = (t >= off) ? sm[t - off] : 0;
        __syncthreads();
        sm[t] += add;
        __syncthreads();
    }
    boff[t] = sm[t] - v;   // exclusive
}

// ---- phase 2: per-bucket histogram + scan + scatter (pairs re-read, no spill) ----
__global__ __launch_bounds__(1024) void phase2_build(
    const uint* __restrict__ pairs, const int* __restrict__ pcur,
    const int* __restrict__ boff,
    int* __restrict__ rp, int* __restrict__ ssrc, int n)
{
    __shared__ int hist[512], cur[512];
    const int k = blockIdx.x;
    const int t = threadIdx.x;
    const int beg = k * BCAP;
    const int cnt = pcur[k] - beg;
    const int bbase = boff[k];
    const int dbase = k << 9;

    if (t < 512) hist[t] = 0;
    __syncthreads();

    for (int i = t; i < cnt; i += 1024)
        atomicAdd(&hist[pairs[beg + i] >> 17], 1);
    __syncthreads();

    int c0 = (t < 512) ? hist[t] : 0;
    for (int off = 1; off < 512; off <<= 1) {
        int add = 0;
        if (t < 512 && t >= off) add = hist[t - off];
        __syncthreads();
        if (t < 512) hist[t] += add;
        __syncthreads();
    }
    if (t < 512) {
        int node = dbase + t;
        if (node < n) rp[node] = bbase + hist[t];
        cur[t] = hist[t] - c0;
    }
    __syncthreads();

    for (int i = t; i < cnt; i += 1024) {
        uint p = pairs[beg + i];      // L2-hot re-read
        int j = p >> 17;
        int pos = bbase + atomicAdd(&cur[j], 1);
        ssrc[pos] = (int)(p & 0x1FFFF);
    }
}

// ---- pull-gather layer 1 (8 heads): octet (8 lanes) per node, 8 ch/lane ----
// lane ol owns head ol exactly (channels 8ol..8ol+7); dsum is its head's denom.
__global__ __launch_bounds__(256) void gather_h8(
    const int* __restrict__ rp, const int* __restrict__ ssrc,
    const float* __restrict__ a_src, const float* __restrict__ a_dst,
    const ushort* __restrict__ HB, const float* __restrict__ bias,
    ushort* __restrict__ HACT, int n)
{
    int node = blockIdx.x * 32 + (threadIdx.x >> 3);
    if (node >= n) return;
    int ol = threadIdx.x & 7;
    int end = rp[node];
    int start = node ? rp[node - 1] : 0;
    float adh = a_dst[(size_t)node * 8 + ol];
    float acc[8] = {};
    float dsum = 0.f;

    for (int i0 = start; i0 < end; i0 += 8) {
        int cnt = min(8, end - i0);
        int sv = (ol < cnt) ? ssrc[i0 + ol] : 0;
        #pragma unroll
        for (int j = 0; j < 8; ++j) {
            int sj = __shfl(sv, j, 8);
            float a = a_src[(size_t)sj * 8 + ol] + adh;
            a = a > 0.f ? a : LRELU_SLOPE * a;
            float e = __expf(a);
            e = (j < cnt) ? e : 0.f;
            dsum += e;
            uint4 hv = *(const uint4*)(HB + (size_t)sj * 64 + ol * 8);
            acc[0] += e * bf2f((ushort)(hv.x & 0xffff));
            acc[1] += e * bf2f((ushort)(hv.x >> 16));
            acc[2] += e * bf2f((ushort)(hv.y & 0xffff));
            acc[3] += e * bf2f((ushort)(hv.y >> 16));
            acc[4] += e * bf2f((ushort)(hv.z & 0xffff));
            acc[5] += e * bf2f((ushort)(hv.z >> 16));
            acc[6] += e * bf2f((ushort)(hv.w & 0xffff));
            acc[7] += e * bf2f((ushort)(hv.w >> 16));
        }
    }
    float inv = 1.f / (dsum + 1e-16f);
    float4 b0 = *(const float4*)(bias + ol * 8);
    float4 b1 = *(const float4*)(bias + ol * 8 + 4);
    float v[8];
    v[0] = acc[0] * inv + b0.x; v[1] = acc[1] * inv + b0.y;
    v[2] = acc[2] * inv + b0.z; v[3] = acc[3] * inv + b0.w;
    v[4] = acc[4] * inv + b1.x; v[5] = acc[5] * inv + b1.y;
    v[6] = acc[6] * inv + b1.z; v[7] = acc[7] * inv + b1.w;
    #pragma unroll
    for (int c = 0; c < 8; ++c) v[c] = v[c] > 0.f ? v[c] : expm1f(v[c]);
    uint4 o;
    o.x = (uint)f2bf(v[0]) | ((uint)f2bf(v[1]) << 16);
    o.y = (uint)f2bf(v[2]) | ((uint)f2bf(v[3]) << 16);
    o.z = (uint)f2bf(v[4]) | ((uint)f2bf(v[5]) << 16);
    o.w = (uint)f2bf(v[6]) | ((uint)f2bf(v[7]) << 16);
    *(uint4*)(HACT + (size_t)node * 64 + ol * 8) = o;
}

// ---- pull-gather layer 2 (1 head): octet per node, 8 ch/lane + lsm ----
__global__ __launch_bounds__(256) void gather_h1_lsm(
    const int* __restrict__ rp, const int* __restrict__ ssrc,
    const float* __restrict__ a_src, const float* __restrict__ a_dst,
    const ushort* __restrict__ HB, const float* __restrict__ bias,
    float* __restrict__ OUT, int n)
{
    int node = blockIdx.x * 32 + (threadIdx.x >> 3);
    if (node >= n) return;
    int ol = threadIdx.x & 7;
    int end = rp[node];
    int start = node ? rp[node - 1] : 0;
    float ad = a_dst[node];
    float acc[8] = {};
    float dsum = 0.f;

    for (int i0 = start; i0 < end; i0 += 8) {
        int cnt = min(8, end - i0);
        int sv = (ol < cnt) ? ssrc[i0 + ol] : 0;
        #pragma unroll
        for (int j = 0; j < 8; ++j) {
            int sj = __shfl(sv, j, 8);
            float a = a_src[sj] + ad;
            a = a > 0.f ? a : LRELU_SLOPE * a;
            float e = __expf(a);
            e = (j < cnt) ? e : 0.f;
            dsum += e;
            uint4 hv = *(const uint4*)(HB + (size_t)sj * 64 + ol * 8);
            acc[0] += e * bf2f((ushort)(hv.x & 0xffff));
            acc[1] += e * bf2f((ushort)(hv.x >> 16));
            acc[2] += e * bf2f((ushort)(hv.y & 0xffff));
            acc[3] += e * bf2f((ushort)(hv.y >> 16));
            acc[4] += e * bf2f((ushort)(hv.z & 0xffff));
            acc[5] += e * bf2f((ushort)(hv.z >> 16));
            acc[6] += e * bf2f((ushort)(hv.w & 0xffff));
            acc[7] += e * bf2f((ushort)(hv.w >> 16));
        }
    }
    float inv = 1.f / (dsum + 1e-16f);
    float4 b0 = *(const float4*)(bias + ol * 8);
    float4 b1 = *(const float4*)(bias + ol * 8 + 4);
    float v[8];
    v[0] = acc[0] * inv + b0.x; v[1] = acc[1] * inv + b0.y;
    v[2] = acc[2] * inv + b0.z; v[3] = acc[3] * inv + b0.w;
    v[4] = acc[4] * inv + b1.x; v[5] = acc[5] * inv + b1.y;
    v[6] = acc[6] * inv + b1.z; v[7] = acc[7] * inv + b1.w;

    float m = v[0];
    #pragma unroll
    for (int c = 1; c < 8; ++c) m = fmaxf(m, v[c]);
    m = fmaxf(m, __shfl_xor(m, 1, 8));
    m = fmaxf(m, __shfl_xor(m, 2, 8));
    m = fmaxf(m, __shfl_xor(m, 4, 8));
    float s = 0.f;
    #pragma unroll
    for (int c = 0; c < 8; ++c) s += __expf(v[c] - m);
    s += __shfl_xor(s, 1, 8);
    s += __shfl_xor(s, 2, 8);
    s += __shfl_xor(s, 4, 8);
    float lse = m + __logf(s);
    float4 o0 = make_float4(v[0] - lse, v[1] - lse, v[2] - lse, v[3] - lse);
    float4 o1 = make_float4(v[4] - lse, v[5] - lse, v[6] - lse, v[7] - lse);
    *(float4*)(OUT + (size_t)node * 64 + ol * 8) = o0;
    *(float4*)(OUT + (size_t)node * 64 + ol * 8 + 4) = o1;
}

extern "C" void kernel_launch(void* const* d_in, const int* in_sizes, int n_in,
                              void* d_out, int out_size, void* d_ws, size_t ws_size,
                              hipStream_t stream)
{
    const float* x    = (const float*)d_in[0];
    const int*   ei   = (const int*)d_in[1];
    const float* W1   = (const float*)d_in[2];
    const float* as1w = (const float*)d_in[3];
    const float* ad1w = (const float*)d_in[4];
    const float* b1   = (const float*)d_in[5];
    const float* W2   = (const float*)d_in[6];
    const float* as2w = (const float*)d_in[7];
    const float* ad2w = (const float*)d_in[8];
    const float* b2   = (const float*)d_in[9];
    float* out = (float*)d_out;

    const int n  = in_sizes[0] / 256;     // 100000
    const int E_ = in_sizes[1] / 2;       // 1600000
    const int ET = E_ + n;
    const int NBUKU = (n + 511) >> 9;     // 196 used buckets

    char* wsb = (char*)d_ws;
    ushort* HACT = (ushort*)wsb;                         // [n*64] bf16 (aliases pairs)
    uint*   pairs= (uint*)wsb;                           // [NBUK*BCAP] build-time only
    ushort* HB   = HACT + (size_t)n * 64;                // [n*64] bf16
    float*  a_s1 = (float*)(HB + (size_t)n * 64);        // [n*8]
    float*  a_d1 = a_s1 + (size_t)n * 8;                 // [n*8]
    float*  a_s2 = a_d1 + (size_t)n * 8;                 // [n]
    float*  a_d2 = a_s2 + n;                             // [n]
    int*    rp   = (int*)(a_d2 + n);                     // [n]
    int*    pcur = rp + n;                               // [NBUK]
    int*    boff = pcur + NBUK;                          // [NBUK]
    int*    ssrc = boff + NBUK;                          // [ET]
    ushort* WT1  = (ushort*)(ssrc + ET);                 // [64*256]
    ushort* WT2  = WT1 + 64 * 256;                       // [64*64]

    const int gemm_grid = (n + 63) / 64;
    const int natt_grid = (n + 3) / 4;
    const int gath_grid = (n + 31) / 32;
    const int part_grid = (ET + CH2 - 1) / CH2;

    // ---- weight prep + CSR build (reused by both layers) ----
    prep_wt<<<80, 256, 0, stream>>>(W1, W2, WT1, WT2);
    init_pcur<<<1, NBUK, 0, stream>>>(pcur);
    partition_pairs<<<part_grid, 1024, 0, stream>>>(ei, E_, ET, pcur, pairs);
    bucket_scan<<<1, NBUK, 0, stream>>>(pcur, boff, NBUKU);
    phase2_build<<<NBUKU, 1024, 0, stream>>>(pairs, pcur, boff, rp, ssrc, n);

    // ---- layer 1 ----
    gemm_mfma<256, true><<<gemm_grid, 256, 0, stream>>>(x, WT1, HB, n);
    node_att_h8<<<natt_grid, 256, 0, stream>>>(HB, as1w, ad1w, a_s1, a_d1, n);
    gather_h8<<<gath_grid, 256, 0, stream>>>(rp, ssrc, a_s1, a_d1, HB, b1, HACT, n);

    // ---- layer 2 ----
    gemm_mfma<64, false><<<gemm_grid, 256, 0, stream>>>(HACT, WT2, HB, n);
    node_att_h1<<<natt_grid, 256, 0, stream>>>(HB, as2w, ad2w, a_s2, a_d2, n);
    gather_h1_lsm<<<gath_grid, 256, 0, stream>>>(rp, ssrc, a_s2, a_d2, HB, b2, out, n);
}